// Round 5
// baseline (329.301 us; speedup 1.0000x reference)
//
#include <hip/hip_runtime.h>
#include <hip/hip_bf16.h>

#define B_ 2
#define T_ 2048
#define DM_ 2048
#define H_ 16
#define KV_ 4
#define HD_ 128
#define M_ 4096   // B_*T_
#define QKVN 3072 // H*HD + 2*KV*HD

typedef __attribute__((ext_vector_type(8))) short bf16x8;
typedef __attribute__((ext_vector_type(4))) float f32x4;
typedef __attribute__((ext_vector_type(4))) short s16x4;
typedef unsigned short u16;
typedef unsigned int u32;
typedef __attribute__((address_space(1))) unsigned int as1_u32;
typedef __attribute__((address_space(3))) unsigned int as3_u32;

__device__ inline u16 f2b(float f){
  __hip_bfloat16 h = __float2bfloat16(f);
  return *reinterpret_cast<u16*>(&h);
}
__device__ inline float b2f(u16 u){
  __hip_bfloat16 h = *reinterpret_cast<__hip_bfloat16*>(&u);
  return __bfloat162float(h);
}
__device__ inline f32x4 mfma16(bf16x8 a, bf16x8 b, f32x4 c){
  return __builtin_amdgcn_mfma_f32_16x16x32_bf16(a, b, c, 0, 0, 0);
}

// ---------------- fp32 -> bf16 convert (vectorized) ----------------
__global__ void cvt_f32_bf16(const float* __restrict__ in, u16* __restrict__ out){
  int i = (blockIdx.x*256 + threadIdx.x)*4;
  float4 v = *reinterpret_cast<const float4*>(in + i);
  s16x4 o;
  o[0] = (short)f2b(v.x); o[1] = (short)f2b(v.y);
  o[2] = (short)f2b(v.z); o[3] = (short)f2b(v.w);
  *reinterpret_cast<s16x4*>(out + i) = o;
}

// ------------- W [K][N] fp32  ->  Wt [N][K] bf16 (LDS tiled) -------------
__global__ void transpose_cvt(const float* __restrict__ W, u16* __restrict__ Wt, int K, int N){
  __shared__ float tile[32][33];
  const int n0 = blockIdx.x*32, k0 = blockIdx.y*32;
  const int tx = threadIdx.x, ty = threadIdx.y;
#pragma unroll
  for (int i=0;i<4;i++)
    tile[ty+8*i][tx] = W[(size_t)(k0+ty+8*i)*N + n0 + tx];
  __syncthreads();
#pragma unroll
  for (int i=0;i<4;i++)
    Wt[(size_t)(n0+ty+8*i)*K + k0 + tx] = f2b(tile[tx][ty+8*i]);
}

// ------------- V region of qkv [row][QKVN] -> vt [(b*KV+kv)*HD + d][T] -------------
__global__ void transpose_v(const u16* __restrict__ vb, u16* __restrict__ vt){
  __shared__ u16 tile[32][33];
  const int t0 = blockIdx.x*32, d0 = blockIdx.y*32, bk = blockIdx.z;
  const int bb = bk >> 2, kv = bk & 3;
  const int tx = threadIdx.x, ty = threadIdx.y;
#pragma unroll
  for (int i=0;i<4;i++)
    tile[ty+8*i][tx] = vb[(size_t)(bb*T_ + t0+ty+8*i)*QKVN + kv*HD_ + d0 + tx];
  __syncthreads();
#pragma unroll
  for (int i=0;i<4;i++)
    vt[(size_t)(bk*HD_ + d0+ty+8*i)*T_ + t0 + tx] = tile[tx][ty+8*i];
}

// ---------------- RoPE: table + vectorized apply ----------------
__global__ void rope_table(float2* __restrict__ tab){
  int idx = blockIdx.x*256 + threadIdx.x;   // t*64 + d, 131072 total
  int t = idx >> 6, d = idx & 63;
  float inv = exp2f((float)d * -0.2076205059304601f);  // 10000^(-d/64)
  float sn, cs;
  sincosf((float)t * inv, &sn, &cs);
  tab[idx] = float2{cs, sn};
}

__global__ void rope_apply(u16* __restrict__ qk, const float2* __restrict__ tab,
                           int lognh, int stride){
  int idx = blockIdx.x*256 + threadIdx.x;
  int dp = idx & 31;            // d pair: d = 2dp, 2dp+1
  int rh = idx >> 5;
  int nh = 1 << lognh;
  int h = rh & (nh-1);
  int row = rh >> lognh;
  if (row >= M_) return;
  int t = row & (T_-1);
  float4 cn = *reinterpret_cast<const float4*>(tab + t*64 + 2*dp); // cs0,sn0,cs1,sn1
  size_t base = (size_t)row*stride + h*HD_ + 2*dp;
  u32 lo = *reinterpret_cast<const u32*>(qk + base);
  u32 hi = *reinterpret_cast<const u32*>(qk + base + 64);
  float a0 = b2f(lo & 0xffff), a1 = b2f(lo >> 16);
  float b0 = b2f(hi & 0xffff), b1 = b2f(hi >> 16);
  u32 nlo = (u32)f2b(a0*cn.x - b0*cn.y) | ((u32)f2b(a1*cn.z - b1*cn.w) << 16);
  u32 nhi = (u32)f2b(b0*cn.x + a0*cn.y) | ((u32)f2b(b1*cn.z + a1*cn.w) << 16);
  *reinterpret_cast<u32*>(qk + base)      = nlo;
  *reinterpret_cast<u32*>(qk + base + 64) = nhi;
}

// ---------------- bf16 GEMM: C[M][N] = A[M][K] * BT[N][K]^T ----------------
__device__ inline void cstore(float* p, float v){ *p = v; }
__device__ inline void cstore(u16* p, float v){ *p = f2b(v); }

template<typename CT>
__global__ __launch_bounds__(256) void gemm_bt(const u16* __restrict__ A, const u16* __restrict__ BT,
                                               CT* __restrict__ C, int M, int N, int K)
{
  __shared__ u16 Als[128*32];
  __shared__ u16 Bls[128*32];
  const int tid = threadIdx.x;
  const int wave = tid>>6, lane = tid&63;
  const int gx = gridDim.x;
  int wid = blockIdx.y*gx + blockIdx.x;
  const int cpx = (gx*gridDim.y) >> 3;
  wid = (wid & 7)*cpx + (wid >> 3);
  const int m0 = (wid / gx)*128, n0 = (wid % gx)*128;
  const int wr = (wave>>1)*64, wc = (wave&1)*64;

  f32x4 acc[4][4];
#pragma unroll
  for (int i=0;i<4;i++)
#pragma unroll
    for (int j=0;j<4;j++) acc[i][j] = f32x4{0.f,0.f,0.f,0.f};

  const int lin0 = ((wave*2+0)*64 + lane)*8;
  const int lin1 = ((wave*2+1)*64 + lane)*8;
  const int r0 = lin0>>5, c0 = lin0&31;
  const int r1 = lin1>>5, c1 = lin1&31;

  for (int k0=0; k0<K; k0+=32){
    __syncthreads();
    __builtin_amdgcn_global_load_lds((as1_u32*)(A  + (size_t)(m0+r0)*K + k0 + c0),
                                     (as3_u32*)(Als + (wave*2+0)*512), 16, 0, 0);
    __builtin_amdgcn_global_load_lds((as1_u32*)(A  + (size_t)(m0+r1)*K + k0 + c1),
                                     (as3_u32*)(Als + (wave*2+1)*512), 16, 0, 0);
    __builtin_amdgcn_global_load_lds((as1_u32*)(BT + (size_t)(n0+r0)*K + k0 + c0),
                                     (as3_u32*)(Bls + (wave*2+0)*512), 16, 0, 0);
    __builtin_amdgcn_global_load_lds((as1_u32*)(BT + (size_t)(n0+r1)*K + k0 + c1),
                                     (as3_u32*)(Bls + (wave*2+1)*512), 16, 0, 0);
    __syncthreads();

    bf16x8 af[4], bfr[4];
#pragma unroll
    for (int mi=0;mi<4;mi++)
      af[mi] = *reinterpret_cast<const bf16x8*>(Als + (wr + mi*16 + (lane&15))*32 + 8*(lane>>4));
#pragma unroll
    for (int ni=0;ni<4;ni++)
      bfr[ni] = *reinterpret_cast<const bf16x8*>(Bls + (wc + ni*16 + (lane&15))*32 + 8*(lane>>4));
#pragma unroll
    for (int mi=0;mi<4;mi++)
#pragma unroll
      for (int ni=0;ni<4;ni++)
        acc[mi][ni] = mfma16(af[mi], bfr[ni], acc[mi][ni]);
  }

#pragma unroll
  for (int mi=0;mi<4;mi++)
#pragma unroll
    for (int ni=0;ni<4;ni++)
#pragma unroll
      for (int j=0;j<4;j++){
        int row = m0 + wr + mi*16 + (lane>>4)*4 + j;
        int col = n0 + wc + ni*16 + (lane&15);
        cstore(C + (size_t)row*N + col, acc[mi][ni][j]);
      }
}

// ---------------- causal GQA flash attention (v4: uniform units, 1 wave/block) ----------------
// Unit = (bh, qt, chunk c): c==0 is the "tail" chunk covering s-tiles [0, L), L=(qt&15)+1;
// c>=1 are full 16-tile chunks [L+16(c-1), L+16c). nc = (qt>>4)+1 chunks total.
// u < 3072: full chunks (launched first). u >= 3072: tails (u = 3072 + bh*64 + qt).
// qt<16 (nc==1) units finalize directly to ao; others write bf16 partials + (m,l).
// Partial slot u: u<4096 -> d_out region, else wT region (dead after QKV GEMM).
__device__ inline u16* slot_ptr(u16* pout, u16* pwt, int u){
  return (u < 4096) ? (pout + (size_t)u*4096) : (pwt + (size_t)(u-4096)*4096);
}

__global__ __launch_bounds__(64) void attn_kernel(const u16* __restrict__ qkv,
                                                  const u16* __restrict__ Vt,
                                                  u16* __restrict__ pout,
                                                  u16* __restrict__ pwt,
                                                  float* __restrict__ ml,
                                                  u16* __restrict__ ao)
{
  __shared__ u16 plds[32*40];
  const int lane = threadIdx.x & 63;
  const int g = lane>>4, qc = lane&15;
  const int u = blockIdx.x;

  int bh, qt, c;
  if (u < 3072){
    bh = u/96; int f = u%96;
    if (f < 16){ qt = 16+f; c = 1; }
    else if (f < 48){ qt = 32+((f-16)>>1); c = 1+((f-16)&1); }
    else { int e = f-48; qt = 48 + e/3; c = 1 + e%3; }
  } else {
    int v = u-3072; bh = v>>6; qt = v&63; c = 0;
  }
  const int nc = (qt>>4)+1;
  const int L  = (qt&15)+1;
  const int t0 = (c==0) ? 0 : (L + 16*(c-1));
  const int cnt = (c==0) ? L : 16;
  const bool lastm = (c == nc-1);

  const int h = bh & (H_-1), b = bh >> 4;
  const int kv = h >> 2;

  const u16* qbase = qkv + (size_t)(b*T_ + qt*32)*QKVN + h*HD_ + 8*g;
  bf16x8 qf[2][4];
#pragma unroll
  for (int qs=0; qs<2; qs++)
#pragma unroll
    for (int d4=0; d4<4; d4++)
      qf[qs][d4] = *reinterpret_cast<const bf16x8*>(qbase + (size_t)(qs*16+qc)*QKVN + d4*32);

  const u16* kbase = qkv + (size_t)(b*T_)*QKVN + 2048 + kv*HD_ + 8*g;
  const u16* vbase = Vt + (size_t)(b*KV_+kv)*HD_*T_ + 8*g;

  f32x4 oacc[2][8];
#pragma unroll
  for (int qs=0; qs<2; qs++)
#pragma unroll
    for (int dt=0; dt<8; dt++) oacc[qs][dt] = f32x4{0.f,0.f,0.f,0.f};
  float mrun[2] = {-1e30f, -1e30f};
  float lrun[2] = {0.f, 0.f};
  const float SCALE = 0.08838834764831845f;
  const float L2E = 1.4426950408889634f;
  u16* pw = &plds[0];

  auto loadK = [&](bf16x8 (&kf)[8], int s0){
#pragma unroll
    for (int ss=0; ss<2; ss++)
#pragma unroll
      for (int d4=0; d4<4; d4++)
        kf[ss*4+d4] = *reinterpret_cast<const bf16x8*>(kbase + (size_t)(s0+ss*16+qc)*QKVN + d4*32);
  };

  auto compute = [&](const bf16x8 (&kf)[8], int s0, bool masked){
    f32x4 sacc[2][2];
#pragma unroll
    for (int qs=0; qs<2; qs++)
#pragma unroll
      for (int ss=0; ss<2; ss++) sacc[qs][ss] = f32x4{0.f,0.f,0.f,0.f};
    __builtin_amdgcn_s_setprio(1);
#pragma unroll
    for (int d4=0; d4<4; d4++)
#pragma unroll
      for (int ss=0; ss<2; ss++)
#pragma unroll
        for (int qs=0; qs<2; qs++)
          sacc[qs][ss] = mfma16(kf[ss*4+d4], qf[qs][d4], sacc[qs][ss]);
    __builtin_amdgcn_s_setprio(0);

    bf16x8 vf[8];
#pragma unroll
    for (int dt=0; dt<8; dt++)
      vf[dt] = *reinterpret_cast<const bf16x8*>(vbase + (size_t)(dt*16+qc)*T_ + s0);

    float p[2][8], al[2], mnew[2];
#pragma unroll
    for (int qs=0; qs<2; qs++){
      float tm = -1e30f;
#pragma unroll
      for (int ss=0; ss<2; ss++)
#pragma unroll
        for (int jj=0; jj<4; jj++){
          float v = sacc[qs][ss][jj]*SCALE;
          if (masked){
            int sg = s0 + ss*16 + g*4 + jj;
            if (sg > qt*32 + qs*16 + qc) v = -1e30f;
          }
          p[qs][ss*4+jj] = v;
          tm = fmaxf(tm, v);
        }
      tm = fmaxf(tm, __shfl_xor(tm, 16));
      tm = fmaxf(tm, __shfl_xor(tm, 32));
      mnew[qs] = fmaxf(mrun[qs], tm);
      al[qs] = exp2f((mrun[qs]-mnew[qs])*L2E);
    }
#pragma unroll
    for (int qs=0; qs<2; qs++){
      float rs = 0.f;
#pragma unroll
      for (int i=0;i<8;i++){ p[qs][i] = exp2f((p[qs][i]-mnew[qs])*L2E); rs += p[qs][i]; }
      rs += __shfl_xor(rs, 16);
      rs += __shfl_xor(rs, 32);
      lrun[qs] = lrun[qs]*al[qs] + rs;
      mrun[qs] = mnew[qs];
    }
    if (!__all((al[0]==1.f) & (al[1]==1.f))){
      float aj0[4], aj1[4];
#pragma unroll
      for (int jj=0; jj<4; jj++){
        aj0[jj] = __shfl(al[0], g*4+jj);
        aj1[jj] = __shfl(al[1], g*4+jj);
      }
#pragma unroll
      for (int dt=0; dt<8; dt++)
#pragma unroll
        for (int jj=0; jj<4; jj++){
          oacc[0][dt][jj] *= aj0[jj];
          oacc[1][dt][jj] *= aj1[jj];
        }
    }
#pragma unroll
    for (int qs=0; qs<2; qs++)
#pragma unroll
      for (int ss=0; ss<2; ss++){
        unsigned w0 = (unsigned)f2b(p[qs][ss*4+0]) | ((unsigned)f2b(p[qs][ss*4+1])<<16);
        unsigned w1 = (unsigned)f2b(p[qs][ss*4+2]) | ((unsigned)f2b(p[qs][ss*4+3])<<16);
        *reinterpret_cast<unsigned*>(pw + (qs*16+qc)*40 + ss*16 + g*4)     = w0;
        *reinterpret_cast<unsigned*>(pw + (qs*16+qc)*40 + ss*16 + g*4 + 2) = w1;
      }
    bf16x8 pf[2];
#pragma unroll
    for (int qs=0; qs<2; qs++)
      pf[qs] = *reinterpret_cast<const bf16x8*>(pw + (qs*16+qc)*40 + 8*g);
    __builtin_amdgcn_s_setprio(1);
#pragma unroll
    for (int dt=0; dt<8; dt++)
#pragma unroll
      for (int qs=0; qs<2; qs++)
        oacc[qs][dt] = mfma16(pf[qs], vf[dt], oacc[qs][dt]);
    __builtin_amdgcn_s_setprio(0);
  };

  {
    bf16x8 kA[8], kB[8];
    int s = t0*32;
    loadK(kA, s);
    int i = 0;
    for (; i+2 < cnt; i+=2, s+=64){
      loadK(kB, s+32); compute(kA, s, false);
      loadK(kA, s+64); compute(kB, s+32, false);
    }
    if (cnt-i == 2){
      loadK(kB, s+32);
      compute(kA, s, false);
      compute(kB, s+32, lastm);
    } else {
      compute(kA, s, lastm);
    }
  }

  if (nc == 1){
    // finalize directly
    float lj0[4], lj1[4];
    float li0 = 1.f/lrun[0], li1 = 1.f/lrun[1];
#pragma unroll
    for (int jj=0; jj<4; jj++){
      lj0[jj] = __shfl(li0, g*4+jj);
      lj1[jj] = __shfl(li1, g*4+jj);
    }
    u16* ob = ao + (size_t)(b*T_ + qt*32)*(H_*HD_) + h*HD_;
#pragma unroll
    for (int dt=0; dt<8; dt++)
#pragma unroll
      for (int jj=0; jj<4; jj++){
        ob[(size_t)(g*4+jj)*(H_*HD_) + dt*16 + qc]      = f2b(oacc[0][dt][jj]*lj0[jj]);
        ob[(size_t)(16 + g*4+jj)*(H_*HD_) + dt*16 + qc] = f2b(oacc[1][dt][jj]*lj1[jj]);
      }
  } else {
    u16* ob = slot_ptr(pout, pwt, u);
#pragma unroll
    for (int qs=0; qs<2; qs++)
#pragma unroll
      for (int dt=0; dt<8; dt++)
#pragma unroll
        for (int jj=0; jj<4; jj++)
          ob[(size_t)(qs*16 + g*4+jj)*128 + dt*16 + qc] = f2b(oacc[qs][dt][jj]);
    if (lane < 16){
      float* mlb = ml + (size_t)u*64;
#pragma unroll
      for (int qs=0; qs<2; qs++){
        mlb[qs*16 + qc]      = mrun[qs];
        mlb[32 + qs*16 + qc] = lrun[qs];
      }
    }
  }
}

// ---------------- combine partials (qt>=16) -> attention output (bf16) ----------------
__global__ void combine_kernel(const u16* __restrict__ pout, const u16* __restrict__ pwt,
                               const float* __restrict__ ml, u16* __restrict__ ao)
{
  const float L2E = 1.4426950408889634f;
  int idx = blockIdx.x*256 + threadIdx.x;   // 786432 threads
  int dg = idx & 15;
  int r  = (idx >> 4) & 31;
  int t  = idx >> 9;            // [0, 1536)
  int bh = t/48, qi = t%48;
  int qt = 16 + qi;
  int nc = (qt>>4)+1;           // 2..4
  int fbase;
  if (qt < 32)      fbase = qt-16;
  else if (qt < 48) fbase = 16 + (qt-32)*2;
  else              fbase = 48 + (qt-48)*3;

  int us[4];
  us[0] = 3072 + bh*64 + qt;    // tail chunk
#pragma unroll
  for (int cc=1; cc<4; cc++) us[cc] = bh*96 + fbase + (cc-1);

  float m[4], l[4];
  float M = -1e30f;
#pragma unroll 4
  for (int cc=0; cc<4; cc++){
    if (cc < nc){
      m[cc] = ml[(size_t)us[cc]*64 + r];
      l[cc] = ml[(size_t)us[cc]*64 + 32 + r];
      M = fmaxf(M, m[cc]);
    }
  }
  float acc[8];
#pragma unroll
  for (int i=0;i<8;i++) acc[i] = 0.f;
  float denom = 0.f;
#pragma unroll 4
  for (int cc=0; cc<4; cc++){
    if (cc < nc){
      float w = exp2f((m[cc]-M)*L2E);
      denom += w*l[cc];
      const u16* sp = (us[cc] < 4096) ? (pout + (size_t)us[cc]*4096) : (pwt + (size_t)(us[cc]-4096)*4096);
      bf16x8 v8 = *reinterpret_cast<const bf16x8*>(sp + (size_t)r*128 + dg*8);
#pragma unroll
      for (int i=0;i<8;i++) acc[i] += w*b2f((u16)v8[i]);
    }
  }
  float inv = 1.f/denom;
  bf16x8 o;
#pragma unroll
  for (int i=0;i<8;i++) o[i] = (short)f2b(acc[i]*inv);
  int b = bh >> 4, h = bh & 15;
  size_t row = (size_t)b*T_ + qt*32 + r;
  *reinterpret_cast<bf16x8*>(ao + row*2048 + h*128 + dg*8) = o;
}

// ---------------- launch ----------------
extern "C" void kernel_launch(void* const* d_in, const int* in_sizes, int n_in,
                              void* d_out, int out_size, void* d_ws, size_t ws_size,
                              hipStream_t stream)
{
  const float* x  = (const float*)d_in[0];
  const float* Wq = (const float*)d_in[1];
  const float* Wk = (const float*)d_in[2];
  const float* Wv = (const float*)d_in[3];
  const float* Wo = (const float*)d_in[4];
  float* out = (float*)d_out;

  char* ws = (char*)d_ws;
  size_t off = 0;
  auto carve = [&](size_t bytes)->void*{
    void* p = ws + off; off += (bytes + 255) & ~(size_t)255; return p;
  };
  u16*    xb   = (u16*)carve((size_t)M_*DM_*2);       // reused as `ao` after QKV GEMM
  u16*    wT   = (u16*)carve((size_t)QKVN*2048*2);    // [Wq;Wk;Wv]^T ; dead after QKV GEMM -> partial slots
  u16*    woT  = (u16*)carve((size_t)2048*2048*2);
  u16*    qkv  = (u16*)carve((size_t)M_*QKVN*2);
  u16*    vt   = (u16*)carve((size_t)M_*512*2);
  float2* tab  = (float2*)carve((size_t)T_*64*8);
  float*  ml   = (float*)carve((size_t)5120*64*4);
  u16*    ao   = xb;                                  // alias: xb dead after QKV GEMM
  u16*    pout = (u16*)d_out;                         // 4096 slots x 8KB, overwritten by final GEMM
  u16*    pwt  = wT;                                  // 1024 slots x 8KB in dead wT region

  cvt_f32_bf16<<<8192, 256, 0, stream>>>(x, xb);
  rope_table<<<512, 256, 0, stream>>>(tab);
  transpose_cvt<<<dim3(64,64), dim3(32,8), 0, stream>>>(Wq, wT,               2048, 2048);
  transpose_cvt<<<dim3(16,64), dim3(32,8), 0, stream>>>(Wk, wT + 2048*2048,   2048, 512);
  transpose_cvt<<<dim3(16,64), dim3(32,8), 0, stream>>>(Wv, wT + 2560*2048,   2048, 512);
  transpose_cvt<<<dim3(64,64), dim3(32,8), 0, stream>>>(Wo, woT,              2048, 2048);

  gemm_bt<u16><<<dim3(24,32), 256, 0, stream>>>(xb, wT, qkv, M_, QKVN, 2048);

  rope_apply<<<8192, 256, 0, stream>>>(qkv,        tab, 4, QKVN);  // Q: 16 heads
  rope_apply<<<2048, 256, 0, stream>>>(qkv + 2048, tab, 2, QKVN);  // K: 4 heads

  transpose_v<<<dim3(64,4,8), dim3(32,8), 0, stream>>>(qkv + 2560, vt);

  attn_kernel<<<5120, 64, 0, stream>>>(qkv, vt, pout, pwt, ml, ao);
  combine_kernel<<<3072, 256, 0, stream>>>(pout, pwt, ml, ao);

  gemm_bt<float><<<dim3(16,32), 256, 0, stream>>>(ao, woT, out, M_, 2048, 2048);
}